// Round 14
// baseline (313.263 us; speedup 1.0000x reference)
//
#include <hip/hip_runtime.h>

typedef __bf16 bf16;
typedef __attribute__((ext_vector_type(8))) __bf16 bf16x8;
typedef __attribute__((ext_vector_type(4))) float f32x4;

// swizzle for [R][32]-bf16 (64B-row) tiles (flash kernel)
static __device__ __forceinline__ int swz4(int r) { return (r >> 1) & 3; }

static __device__ __forceinline__ void async_cp16(void* lds, const void* g) {
  __builtin_amdgcn_global_load_lds((__attribute__((address_space(1))) void*)g,
                                   (__attribute__((address_space(3))) void*)lds,
                                   16, 0, 0);
}

static __device__ __forceinline__ f32x4 mfma16(bf16x8 a, bf16x8 b, f32x4 c) {
  return __builtin_amdgcn_mfma_f32_16x16x32_bf16(a, b, c, 0, 0, 0);
}

static __device__ __forceinline__ unsigned short bfbits(float f) {
  bf16 b = (bf16)f;
  return __builtin_bit_cast(unsigned short, b);
}

// ---------------- fused prep: 7 weight conversions + rope table, one launch ----------------
// NOTE: wq/wk get hi+lo split — the score path REQUIRES it (R9: FFN amplifies
// residual-stream errors ~20x; score-error budget ~0.05 sigma).
extern "C" __global__ void prep_kernel(
    const float* __restrict__ wq, const float* __restrict__ wk,
    const float* __restrict__ wv, const float* __restrict__ wo,
    const float* __restrict__ w1, const float* __restrict__ w3,
    const float* __restrict__ w2,
    unsigned short* __restrict__ WQH, unsigned short* __restrict__ WQL,
    unsigned short* __restrict__ WKH, unsigned short* __restrict__ WKL,
    unsigned short* __restrict__ WVH, unsigned short* __restrict__ WOH,
    unsigned short* __restrict__ W1H, unsigned short* __restrict__ W3H,
    unsigned short* __restrict__ W2H, float2* __restrict__ rope) {
  const int seg = blockIdx.y;
  const int i = blockIdx.x * 256 + threadIdx.x;
  if (seg == 7) {
    if (i >= 32768) return;
    int s = i >> 5, fi = i & 31;
    float inv_freq = powf(10000.0f, -(2.0f * (float)fi) / 64.0f);
    float ang = (float)s * inv_freq;
    float2 cs;
    cs.x = cosf(ang);
    cs.y = sinf(ang);
    rope[i] = cs;
    return;
  }
  const float* src;
  unsigned short* hi_;
  unsigned short* lo_ = nullptr;
  int n4;
  switch (seg) {
    case 0: src = wq; hi_ = WQH; lo_ = WQL; n4 = 262144; break;
    case 1: src = wk; hi_ = WKH; lo_ = WKL; n4 = 262144; break;
    case 2: src = wv; hi_ = WVH; n4 = 262144; break;
    case 3: src = wo; hi_ = WOH; n4 = 262144; break;
    case 4: src = w1; hi_ = W1H; n4 = 1048576; break;
    case 5: src = w3; hi_ = W3H; n4 = 1048576; break;
    default: src = w2; hi_ = W2H; n4 = 1048576; break;
  }
  if (i >= n4) return;
  float4 v = ((const float4*)src)[i];
  bf16 b0 = (bf16)v.x, b1 = (bf16)v.y, b2 = (bf16)v.z, b3 = (bf16)v.w;
  ushort4 oh;
  oh.x = __builtin_bit_cast(unsigned short, b0);
  oh.y = __builtin_bit_cast(unsigned short, b1);
  oh.z = __builtin_bit_cast(unsigned short, b2);
  oh.w = __builtin_bit_cast(unsigned short, b3);
  ((ushort4*)hi_)[i] = oh;
  if (lo_) {
    ushort4 ol;
    ol.x = bfbits(v.x - (float)b0);
    ol.y = bfbits(v.y - (float)b1);
    ol.z = bfbits(v.z - (float)b2);
    ol.w = bfbits(v.w - (float)b3);
    ((ushort4*)lo_)[i] = ol;
  }
}

// rms_norm; optionally also copies x into xcopy (f32) — used to pre-init
// out = x so the wo-projection can run as split-K atomicAdd at 2 blocks/CU.
extern "C" __global__ __launch_bounds__(256) void rmsnorm_kernel(
    const float* __restrict__ x, const float* __restrict__ g,
    unsigned short* __restrict__ yhi, unsigned short* __restrict__ ylo,
    float* __restrict__ xcopy) {
  int row = blockIdx.x;
  int t = threadIdx.x;
  const float4 xv = *(const float4*)(x + (size_t)row * 1024 + t * 4);
  float ss = xv.x * xv.x + xv.y * xv.y + xv.z * xv.z + xv.w * xv.w;
#pragma unroll
  for (int d = 1; d < 64; d <<= 1) ss += __shfl_xor(ss, d, 64);
  __shared__ float red[4];
  if ((t & 63) == 0) red[t >> 6] = ss;
  __syncthreads();
  float tot = red[0] + red[1] + red[2] + red[3];
  float inv = 1.0f / sqrtf(tot * (1.0f / 1024.0f) + 1e-5f);
  const float4 gv = *(const float4*)(g + t * 4);
  float y0 = xv.x * gv.x * inv, y1 = xv.y * gv.y * inv;
  float y2 = xv.z * gv.z * inv, y3 = xv.w * gv.w * inv;
  bf16 b0 = (bf16)y0, b1 = (bf16)y1, b2 = (bf16)y2, b3 = (bf16)y3;
  ushort4 oh;
  oh.x = __builtin_bit_cast(unsigned short, b0);
  oh.y = __builtin_bit_cast(unsigned short, b1);
  oh.z = __builtin_bit_cast(unsigned short, b2);
  oh.w = __builtin_bit_cast(unsigned short, b3);
  ((ushort4*)yhi)[(size_t)row * 256 + t] = oh;
  if (ylo) {
    ushort4 ol;
    ol.x = bfbits(y0 - (float)b0);
    ol.y = bfbits(y1 - (float)b1);
    ol.z = bfbits(y2 - (float)b2);
    ol.w = bfbits(y3 - (float)b3);
    ((ushort4*)ylo)[(size_t)row * 256 + t] = ol;
  }
  if (xcopy) *(float4*)(xcopy + (size_t)row * 1024 + t * 4) = xv;
}

// ---------------- GEMM: C[M,N] = A[M,K(ldk)] * B[N,K(ldk)]^T, 128x128 tile, BK=64 ----------------
// [128][64] LDS tiles, 128B rows, swizzle c ^= r&7. Single-buffered (R11: dbuf
// gains nothing — __syncthreads drains vmcnt(0) incl. the prefetch).
// Flat grid, XCD-chunked M-slab. z = sq>>5 = K-slice for split-K.
// EPI 5: atomicAdd f32 (wo and down-proj; out pre-initialized with residual)
template <int EPI>
__global__ __launch_bounds__(256, 2) void gemm_nt(
    const bf16* __restrict__ A, const bf16* __restrict__ B, int N, int K, int ldk,
    float* __restrict__ outF) {
  const int bid = blockIdx.x;
  const int xcd = bid & 7, sq = bid >> 3;
  const int z = sq >> 5;
  const int rem = sq & 31;
  const size_t tm = (size_t)(xcd * 4 + (rem >> 3)) * 128;
  const size_t tn = (size_t)(rem & 7) * 128;
  A += (size_t)z * K;
  B += (size_t)z * K;
  __shared__ alignas(16) bf16 As[128 * 64];
  __shared__ alignas(16) bf16 Bs[128 * 64];
  const int tid = threadIdx.x;
  const int lane = tid & 63, wave = tid >> 6;
  const int lo = lane & 15, hi = lane >> 4;
  const int wm = wave >> 1, wn = wave & 1;
  f32x4 acc[4][4] = {};
  for (int k0 = 0; k0 < K; k0 += 64) {
    __syncthreads();
#pragma unroll
    for (int i4 = 0; i4 < 4; i4++) {
      int p = tid + 256 * i4;
      int row = p >> 3, c = p & 7;
      int cs = c ^ (row & 7);
      async_cp16((char*)As + (size_t)p * 16, A + (tm + row) * (size_t)ldk + k0 + cs * 8);
      async_cp16((char*)Bs + (size_t)p * 16, B + (tn + row) * (size_t)ldk + k0 + cs * 8);
    }
    __syncthreads();
#pragma unroll
    for (int kh = 0; kh < 2; kh++) {
      bf16x8 fa[4], fb[4];
#pragma unroll
      for (int i = 0; i < 4; i++) {
        int ra = wm * 64 + i * 16 + lo;
        fa[i] = *(const bf16x8*)((const char*)As + ra * 128 + (((kh * 4 + hi) ^ (ra & 7)) << 4));
        int rb = wn * 64 + i * 16 + lo;
        fb[i] = *(const bf16x8*)((const char*)Bs + rb * 128 + (((kh * 4 + hi) ^ (rb & 7)) << 4));
      }
      __builtin_amdgcn_s_setprio(1);
#pragma unroll
      for (int i = 0; i < 4; i++)
#pragma unroll
        for (int j = 0; j < 4; j++) acc[i][j] = mfma16(fa[i], fb[j], acc[i][j]);
      __builtin_amdgcn_s_setprio(0);
    }
  }
#pragma unroll
  for (int i = 0; i < 4; i++)
#pragma unroll
    for (int j = 0; j < 4; j++)
#pragma unroll
      for (int r = 0; r < 4; r++) {
        size_t m = tm + wm * 64 + i * 16 + hi * 4 + r;
        size_t n = tn + wn * 64 + j * 16 + lo;
        atomicAdd(&outF[m * (size_t)N + n], acc[i][j][r]);
      }
}

// ---------------- fused FFN-up: G = silu(A*B1^T) * (A*B3^T), 128x128, BK=64 ----------------
// Single-buffered 3-stream LDS (48KB, 2 blocks/CU) — the measured local optimum.
extern "C" __global__ __launch_bounds__(256, 2) void gemm_up_kernel(
    const bf16* __restrict__ A, const bf16* __restrict__ B1,
    const bf16* __restrict__ B3, bf16* __restrict__ G) {
  const int bid = blockIdx.x;
  const int xcd = bid & 7, sq = bid >> 3;
  const size_t tm = (size_t)(xcd * 4 + (sq & 3)) * 128;
  const size_t tn = (size_t)(sq >> 2) * 128;
  __shared__ alignas(16) bf16 As[128 * 64];
  __shared__ alignas(16) bf16 B1s[128 * 64];
  __shared__ alignas(16) bf16 B3s[128 * 64];
  const int tid = threadIdx.x;
  const int lane = tid & 63, wave = tid >> 6;
  const int lo = lane & 15, hi = lane >> 4;
  const int wm = wave >> 1, wn = wave & 1;
  f32x4 acc1[4][4] = {}, acc3[4][4] = {};
  for (int k0 = 0; k0 < 1024; k0 += 64) {
    __syncthreads();
#pragma unroll
    for (int i4 = 0; i4 < 4; i4++) {
      int p = tid + 256 * i4;
      int row = p >> 3, c = p & 7;
      int cs = c ^ (row & 7);
      async_cp16((char*)As + (size_t)p * 16, A + (tm + row) * (size_t)1024 + k0 + cs * 8);
      async_cp16((char*)B1s + (size_t)p * 16, B1 + (tn + row) * (size_t)1024 + k0 + cs * 8);
      async_cp16((char*)B3s + (size_t)p * 16, B3 + (tn + row) * (size_t)1024 + k0 + cs * 8);
    }
    __syncthreads();
#pragma unroll
    for (int kh = 0; kh < 2; kh++) {
      bf16x8 fa[4], fb[4];
#pragma unroll
      for (int i = 0; i < 4; i++) {
        int ra = wm * 64 + i * 16 + lo;
        fa[i] = *(const bf16x8*)((const char*)As + ra * 128 + (((kh * 4 + hi) ^ (ra & 7)) << 4));
        int rb = wn * 64 + i * 16 + lo;
        fb[i] = *(const bf16x8*)((const char*)B1s + rb * 128 + (((kh * 4 + hi) ^ (rb & 7)) << 4));
      }
      __builtin_amdgcn_s_setprio(1);
#pragma unroll
      for (int i = 0; i < 4; i++)
#pragma unroll
        for (int j = 0; j < 4; j++) acc1[i][j] = mfma16(fa[i], fb[j], acc1[i][j]);
      __builtin_amdgcn_s_setprio(0);
#pragma unroll
      for (int j = 0; j < 4; j++) {
        int rb = wn * 64 + j * 16 + lo;
        fb[j] = *(const bf16x8*)((const char*)B3s + rb * 128 + (((kh * 4 + hi) ^ (rb & 7)) << 4));
      }
      __builtin_amdgcn_s_setprio(1);
#pragma unroll
      for (int i = 0; i < 4; i++)
#pragma unroll
        for (int j = 0; j < 4; j++) acc3[i][j] = mfma16(fa[i], fb[j], acc3[i][j]);
      __builtin_amdgcn_s_setprio(0);
    }
  }
#pragma unroll
  for (int i = 0; i < 4; i++)
#pragma unroll
    for (int j = 0; j < 4; j++)
#pragma unroll
      for (int r = 0; r < 4; r++) {
        size_t m = tm + wm * 64 + i * 16 + hi * 4 + r;
        size_t n = tn + wn * 64 + j * 16 + lo;
        float v1 = acc1[i][j][r], v3 = acc3[i][j][r];
        G[m * 4096 + n] = (bf16)(v1 / (1.0f + __expf(-v1)) * v3);
      }
}

// ---------------- merged QKV: split-precision q/k (3-term, fused RoPE) + plain v (transpose) ----------------
// Grid 768 flat; z INTERLEAVED (z = sq%3) so heavy qk blocks and light v blocks
// are co-resident (fixes the all-light last residency wave of R13). XCD-slab
// decode preserved (xcd = bid&7).
extern "C" __global__ __launch_bounds__(256, 2) void gemm_qkv_kernel(
    const bf16* __restrict__ Ah, const bf16* __restrict__ Al,
    const bf16* __restrict__ BhQ, const bf16* __restrict__ BlQ,
    const bf16* __restrict__ BhK, const bf16* __restrict__ BlK,
    const bf16* __restrict__ BV,
    const float2* __restrict__ rope,
    bf16* __restrict__ OhQ, bf16* __restrict__ OlQ,
    bf16* __restrict__ OhK, bf16* __restrict__ OlK,
    bf16* __restrict__ Vt) {
  const int bid = blockIdx.x;
  const int xcd = bid & 7, sq = bid >> 3;  // sq 0..95
  const int z = sq % 3;                    // 0:Q 1:K 2:V (interleaved)
  const int t = sq / 3;                    // 0..31
  const size_t tm = (size_t)(xcd * 4 + (t >> 3)) * 128;
  const size_t tn = (size_t)(t & 7) * 128;
  const bf16* Bh = (z == 0) ? BhQ : (z == 1) ? BhK : BV;
  const bf16* Bl = (z == 1) ? BlK : BlQ;  // unused when z==2
  __shared__ alignas(16) bf16 Ahs[128 * 64], Als[128 * 64];
  __shared__ alignas(16) bf16 Bhs[128 * 64], Bls[128 * 64];
  const int tid = threadIdx.x;
  const int lane = tid & 63, wave = tid >> 6;
  const int lo = lane & 15, hi = lane >> 4;
  const int wm = wave >> 1, wn = wave & 1;
  const int K = 1024;
  f32x4 acc[4][4] = {};
  for (int k0 = 0; k0 < K; k0 += 64) {
    __syncthreads();
#pragma unroll
    for (int i4 = 0; i4 < 4; i4++) {
      int p = tid + 256 * i4;
      int row = p >> 3, c = p & 7;
      int cs = c ^ (row & 7);
      size_t ga = (tm + row) * (size_t)K + k0 + cs * 8;
      size_t gb = (tn + row) * (size_t)K + k0 + cs * 8;
      async_cp16((char*)Ahs + (size_t)p * 16, Ah + ga);
      async_cp16((char*)Bhs + (size_t)p * 16, Bh + gb);
      if (z < 2) {
        async_cp16((char*)Als + (size_t)p * 16, Al + ga);
        async_cp16((char*)Bls + (size_t)p * 16, Bl + gb);
      }
    }
    __syncthreads();
#pragma unroll
    for (int kh = 0; kh < 2; kh++) {
      int offa[4], offb[4];
#pragma unroll
      for (int i = 0; i < 4; i++) {
        int ra = wm * 64 + i * 16 + lo;
        offa[i] = ra * 128 + (((kh * 4 + hi) ^ (ra & 7)) << 4);
        int rb = wn * 64 + i * 16 + lo;
        offb[i] = rb * 128 + (((kh * 4 + hi) ^ (rb & 7)) << 4);
      }
      bf16x8 fah[4], fbh[4], fx[4];
#pragma unroll
      for (int i = 0; i < 4; i++) {
        fah[i] = *(const bf16x8*)((const char*)Ahs + offa[i]);
        fbh[i] = *(const bf16x8*)((const char*)Bhs + offb[i]);
      }
      __builtin_amdgcn_s_setprio(1);
#pragma unroll
      for (int i = 0; i < 4; i++)
#pragma unroll
        for (int j = 0; j < 4; j++) acc[i][j] = mfma16(fah[i], fbh[j], acc[i][j]);
      __builtin_amdgcn_s_setprio(0);
      if (z < 2) {
#pragma unroll
        for (int j = 0; j < 4; j++) fx[j] = *(const bf16x8*)((const char*)Bls + offb[j]);
        __builtin_amdgcn_s_setprio(1);
#pragma unroll
        for (int i = 0; i < 4; i++)
#pragma unroll
          for (int j = 0; j < 4; j++) acc[i][j] = mfma16(fah[i], fx[j], acc[i][j]);
        __builtin_amdgcn_s_setprio(0);
#pragma unroll
        for (int i = 0; i < 4; i++) fx[i] = *(const bf16x8*)((const char*)Als + offa[i]);
        __builtin_amdgcn_s_setprio(1);
#pragma unroll
        for (int i = 0; i < 4; i++)
#pragma unroll
          for (int j = 0; j < 4; j++) acc[i][j] = mfma16(fx[i], fbh[j], acc[i][j]);
        __builtin_amdgcn_s_setprio(0);
      }
    }
  }
  if (z < 2) {
    bf16* Oh = z ? OhK : OhQ;
    bf16* Ol = z ? OlK : OlQ;
#pragma unroll
    for (int i = 0; i < 4; i++)
#pragma unroll
      for (int j = 0; j < 4; j++)
#pragma unroll
        for (int r = 0; r < 4; r++) {
          float v = acc[i][j][r];
          float vp = __shfl_xor(v, 1, 64);
          size_t m = tm + wm * 64 + i * 16 + hi * 4 + r;
          size_t n = tn + wn * 64 + j * 16 + lo;
          int s = (int)(m & 1023);
          int pi = (int)((n & 63) >> 1);
          float2 cs = rope[s * 32 + pi];
          float res = (n & 1) ? (vp * cs.y + v * cs.x) : (v * cs.x - vp * cs.y);
          size_t idx = (((m >> 10) * 16 + (n >> 6)) * 1024 + (m & 1023)) * 64 + (n & 63);
          bf16 hb = (bf16)res;
          Oh[idx] = hb;
          Ol[idx] = (bf16)(res - (float)hb);
        }
  } else {
#pragma unroll
    for (int i = 0; i < 4; i++)
#pragma unroll
      for (int j = 0; j < 4; j++)
#pragma unroll
        for (int r = 0; r < 4; r++) {
          size_t m = tm + wm * 64 + i * 16 + hi * 4 + r;
          size_t n = tn + wn * 64 + j * 16 + lo;
          size_t idx = (((m >> 10) * 16 + (n >> 6)) * 64 + (n & 63)) * 1024 + (m & 1023);
          Vt[idx] = (bf16)acc[i][j][r];
        }
  }
}

// ---------------- flash attention (causal), split-precision scores, LDS-staged K/V ----------------
extern "C" __global__ __launch_bounds__(256, 4) void flash_kernel(
    const bf16* __restrict__ qhi, const bf16* __restrict__ qlo,
    const bf16* __restrict__ khi, const bf16* __restrict__ klo,
    const bf16* __restrict__ vT, bf16* __restrict__ ctx) {
  const int bid = blockIdx.x;
  const int qb = bid >> 6;
  const int bh = bid & 63;
  const int tid = threadIdx.x;
  const int wave = tid >> 6, lane = tid & 63;
  const int lo = lane & 15, hi = lane >> 4;

  __shared__ alignas(16) bf16 Ksh[2][64][32];
  __shared__ alignas(16) bf16 Ksl[2][64][32];
  __shared__ alignas(16) bf16 Vs[2][64][32];
  __shared__ alignas(16) bf16 P[4][16][72];

  size_t qoff = ((size_t)bh * 1024 + qb * 64 + wave * 16 + lo) * 64;
  bf16x8 qh[2], ql[2];
#pragma unroll
  for (int ks = 0; ks < 2; ks++) {
    qh[ks] = *(const bf16x8*)(qhi + qoff + ks * 32 + hi * 8);
    ql[ks] = *(const bf16x8*)(qlo + qoff + ks * 32 + hi * 8);
  }

  const int srow = tid >> 2;
  const int scl = (tid & 3) ^ swz4(srow);
  const size_t kgb = (size_t)bh * 1024 * 64;
  const size_t vgb = ((size_t)bh * 64 + srow) * 1024;

  float mrun[4] = {-1e30f, -1e30f, -1e30f, -1e30f};
  float lrun[4] = {0.f, 0.f, 0.f, 0.f};
  f32x4 o[4] = {};
  const float scale = 0.125f;

  for (int kt = 0; kt <= qb; kt++) {
    __syncthreads();
#pragma unroll
    for (int i = 0; i < 2; i++) {
      int p = tid + 256 * i;
      size_t gk = kgb + (size_t)(kt * 64 + srow) * 64 + i * 32 + scl * 8;
      async_cp16((char*)Ksh + (size_t)p * 16, khi + gk);
      async_cp16((char*)Ksl + (size_t)p * 16, klo + gk);
      async_cp16((char*)Vs + (size_t)p * 16, vT + vgb + kt * 64 + i * 32 + scl * 8);
    }
    __syncthreads();

    f32x4 sv[4];
    __builtin_amdgcn_s_setprio(1);
#pragma unroll
    for (int nb = 0; nb < 4; nb++) {
      f32x4 a = {0.f, 0.f, 0.f, 0.f};
#pragma unroll
      for (int ks = 0; ks < 2; ks++) {
        int row = nb * 16 + lo;
        int off16 = (ks * 64 + row) * 4 + (hi ^ swz4(row));
        bf16x8 kh = *(const bf16x8*)((const char*)Ksh + off16 * 16);
        bf16x8 kl = *(const bf16x8*)((const char*)Ksl + off16 * 16);
        a = mfma16(qh[ks], kh, a);
        a = mfma16(qh[ks], kl, a);
        a = mfma16(ql[ks], kh, a);
      }
      sv[nb] = a;
    }
    __builtin_amdgcn_s_setprio(0);

    const bool mt = (kt == qb);
#pragma unroll
    for (int nb = 0; nb < 4; nb++)
#pragma unroll
      for (int r = 0; r < 4; r++) {
        float s = sv[nb][r] * scale;
        if (mt) {
          int kp = nb * 16 + lo;
          int qr = wave * 16 + hi * 4 + r;
          if (kp > qr) s = -1e30f;
        }
        sv[nb][r] = s;
      }
    float mnew[4], rs[4];
#pragma unroll
    for (int r = 0; r < 4; r++) {
      float mx = fmaxf(fmaxf(sv[0][r], sv[1][r]), fmaxf(sv[2][r], sv[3][r]));
#pragma unroll
      for (int d = 1; d < 16; d <<= 1) mx = fmaxf(mx, __shfl_xor(mx, d, 64));
      mnew[r] = fmaxf(mrun[r], mx);
      float sc = __expf(mrun[r] - mnew[r]);
      lrun[r] *= sc;
#pragma unroll
      for (int db = 0; db < 4; db++) o[db][r] *= sc;
      mrun[r] = mnew[r];
      rs[r] = 0.f;
    }
#pragma unroll
    for (int nb = 0; nb < 4; nb++)
#pragma unroll
      for (int r = 0; r < 4; r++) {
        float p = __expf(sv[nb][r] - mnew[r]);
        bf16 pb = (bf16)p;
        rs[r] += (float)pb;
        P[wave][hi * 4 + r][nb * 16 + lo] = pb;
      }
#pragma unroll
    for (int r = 0; r < 4; r++) {
      float t = rs[r];
#pragma unroll
      for (int d = 1; d < 16; d <<= 1) t += __shfl_xor(t, d, 64);
      lrun[r] += t;
    }
    bf16x8 pa[2];
#pragma unroll
    for (int ks = 0; ks < 2; ks++) pa[ks] = *(const bf16x8*)&P[wave][lo][ks * 32 + hi * 8];
    __builtin_amdgcn_s_setprio(1);
#pragma unroll
    for (int db = 0; db < 4; db++)
#pragma unroll
      for (int ks = 0; ks < 2; ks++) {
        int row = db * 16 + lo;
        int off16 = (ks * 64 + row) * 4 + (hi ^ swz4(row));
        bf16x8 vf = *(const bf16x8*)((const char*)Vs + off16 * 16);
        o[db] = mfma16(pa[ks], vf, o[db]);
      }
    __builtin_amdgcn_s_setprio(0);
  }
  int b = bh >> 4, h = bh & 15;
#pragma unroll
  for (int db = 0; db < 4; db++)
#pragma unroll
    for (int r = 0; r < 4; r++) {
      float val = o[db][r] / lrun[r];
      size_t row = (size_t)b * 1024 + qb * 64 + wave * 16 + hi * 4 + r;
      ctx[row * 1024 + h * 64 + db * 16 + lo] = (bf16)val;
    }
}

// ---------------- host launcher ----------------

extern "C" void kernel_launch(void* const* d_in, const int* in_sizes, int n_in,
                              void* d_out, int out_size, void* d_ws, size_t ws_size,
                              hipStream_t stream) {
  (void)in_sizes; (void)n_in; (void)out_size; (void)ws_size;
  const float* x  = (const float*)d_in[0];
  const float* wq = (const float*)d_in[1];
  const float* wk = (const float*)d_in[2];
  const float* wv = (const float*)d_in[3];
  const float* wo = (const float*)d_in[4];
  const float* w1 = (const float*)d_in[5];
  const float* w2 = (const float*)d_in[6];
  const float* w3 = (const float*)d_in[7];
  const float* g1 = (const float*)d_in[8];
  const float* g2 = (const float*)d_in[9];
  float* out = (float*)d_out;

  char* ws = (char*)d_ws;
  size_t off = 0;
  auto alloc = [&](size_t bytes) {
    char* p = ws + off;
    off += (bytes + 255) & ~(size_t)255;
    return p;
  };
  const size_t MB2 = 1024u * 1024u * 2u;
  const size_t MB8 = 4096u * 1024u * 2u;
  void* WQH = alloc(MB2);  void* WQL = alloc(MB2);
  void* WKH = alloc(MB2);  void* WKL = alloc(MB2);
  void* WVH = alloc(MB2);  void* WOH = alloc(MB2);
  void* W1H = alloc(MB8);  void* W3H = alloc(MB8);  void* W2H = alloc(MB8);
  void* ROPE = alloc(32768u * 8u);
  void* Y1H = alloc(MB8);  void* Y1L = alloc(MB8);
  void* QH = alloc(MB8);   void* QL = alloc(MB8);
  void* KH = alloc(MB8);   void* KL = alloc(MB8);
  void* VT = alloc(MB8);
  void* CTX = alloc(MB8);
  void* Y2H = alloc(MB8);
  void* GLU = QH;  // 32MB alias over QH,QL,KH,KL (dead after flash)

  prep_kernel<<<dim3(4096, 8), dim3(256), 0, stream>>>(
      wq, wk, wv, wo, w1, w3, w2,
      (unsigned short*)WQH, (unsigned short*)WQL, (unsigned short*)WKH,
      (unsigned short*)WKL, (unsigned short*)WVH, (unsigned short*)WOH,
      (unsigned short*)W1H, (unsigned short*)W3H, (unsigned short*)W2H,
      (float2*)ROPE);

  // rmsnorm1 also pre-initializes out = x (enables split-K atomic wo)
  rmsnorm_kernel<<<dim3(4096), dim3(256), 0, stream>>>(
      x, g1, (unsigned short*)Y1H, (unsigned short*)Y1L, out);

  // merged QKV: q,k split-precision (3-term) + v plain; z interleaved
  gemm_qkv_kernel<<<dim3(768), dim3(256), 0, stream>>>(
      (const bf16*)Y1H, (const bf16*)Y1L,
      (const bf16*)WQH, (const bf16*)WQL, (const bf16*)WKH, (const bf16*)WKL,
      (const bf16*)WVH,
      (const float2*)ROPE,
      (bf16*)QH, (bf16*)QL, (bf16*)KH, (bf16*)KL, (bf16*)VT);

  flash_kernel<<<dim3(1024), dim3(256), 0, stream>>>(
      (const bf16*)QH, (const bf16*)QL, (const bf16*)KH, (const bf16*)KL,
      (const bf16*)VT, (bf16*)CTX);

  // wo-projection: split-K=2 (512 blocks, K=512), atomicAdd into out (= x)
  gemm_nt<5><<<dim3(512), dim3(256), 0, stream>>>(
      (const bf16*)CTX, (const bf16*)WOH, 1024, 512, 1024, out);

  rmsnorm_kernel<<<dim3(4096), dim3(256), 0, stream>>>(
      out, g2, (unsigned short*)Y2H, nullptr, nullptr);

  gemm_up_kernel<<<dim3(1024), dim3(256), 0, stream>>>(
      (const bf16*)Y2H, (const bf16*)W1H, (const bf16*)W3H, (bf16*)GLU);

  // down-projection: split-K=2 (512 blocks, K=2048), atomicAdd into out
  gemm_nt<5><<<dim3(512), dim3(256), 0, stream>>>(
      (const bf16*)GLU, (const bf16*)W2H, 1024, 2048, 4096, out);
}

// Round 15
// 285.411 us; speedup vs baseline: 1.0976x; 1.0976x over previous
//
#include <hip/hip_runtime.h>

typedef __bf16 bf16;
typedef __attribute__((ext_vector_type(8))) __bf16 bf16x8;
typedef __attribute__((ext_vector_type(4))) float f32x4;

// swizzle for [R][32]-bf16 (64B-row) tiles (flash kernel)
static __device__ __forceinline__ int swz4(int r) { return (r >> 1) & 3; }

static __device__ __forceinline__ void async_cp16(void* lds, const void* g) {
  __builtin_amdgcn_global_load_lds((__attribute__((address_space(1))) void*)g,
                                   (__attribute__((address_space(3))) void*)lds,
                                   16, 0, 0);
}

static __device__ __forceinline__ f32x4 mfma16(bf16x8 a, bf16x8 b, f32x4 c) {
  return __builtin_amdgcn_mfma_f32_16x16x32_bf16(a, b, c, 0, 0, 0);
}

static __device__ __forceinline__ unsigned short bfbits(float f) {
  bf16 b = (bf16)f;
  return __builtin_bit_cast(unsigned short, b);
}

// ---------------- fused prep: 7 weight conversions + rope table, one launch ----------------
// NOTE: wq/wk get hi+lo split — the score path REQUIRES it (R9: FFN amplifies
// residual-stream errors ~20x; score-error budget ~0.05 sigma).
extern "C" __global__ void prep_kernel(
    const float* __restrict__ wq, const float* __restrict__ wk,
    const float* __restrict__ wv, const float* __restrict__ wo,
    const float* __restrict__ w1, const float* __restrict__ w3,
    const float* __restrict__ w2,
    unsigned short* __restrict__ WQH, unsigned short* __restrict__ WQL,
    unsigned short* __restrict__ WKH, unsigned short* __restrict__ WKL,
    unsigned short* __restrict__ WVH, unsigned short* __restrict__ WOH,
    unsigned short* __restrict__ W1H, unsigned short* __restrict__ W3H,
    unsigned short* __restrict__ W2H, float2* __restrict__ rope) {
  const int seg = blockIdx.y;
  const int i = blockIdx.x * 256 + threadIdx.x;
  if (seg == 7) {
    if (i >= 32768) return;
    int s = i >> 5, fi = i & 31;
    float inv_freq = powf(10000.0f, -(2.0f * (float)fi) / 64.0f);
    float ang = (float)s * inv_freq;
    float2 cs;
    cs.x = cosf(ang);
    cs.y = sinf(ang);
    rope[i] = cs;
    return;
  }
  const float* src;
  unsigned short* hi_;
  unsigned short* lo_ = nullptr;
  int n4;
  switch (seg) {
    case 0: src = wq; hi_ = WQH; lo_ = WQL; n4 = 262144; break;
    case 1: src = wk; hi_ = WKH; lo_ = WKL; n4 = 262144; break;
    case 2: src = wv; hi_ = WVH; n4 = 262144; break;
    case 3: src = wo; hi_ = WOH; n4 = 262144; break;
    case 4: src = w1; hi_ = W1H; n4 = 1048576; break;
    case 5: src = w3; hi_ = W3H; n4 = 1048576; break;
    default: src = w2; hi_ = W2H; n4 = 1048576; break;
  }
  if (i >= n4) return;
  float4 v = ((const float4*)src)[i];
  bf16 b0 = (bf16)v.x, b1 = (bf16)v.y, b2 = (bf16)v.z, b3 = (bf16)v.w;
  ushort4 oh;
  oh.x = __builtin_bit_cast(unsigned short, b0);
  oh.y = __builtin_bit_cast(unsigned short, b1);
  oh.z = __builtin_bit_cast(unsigned short, b2);
  oh.w = __builtin_bit_cast(unsigned short, b3);
  ((ushort4*)hi_)[i] = oh;
  if (lo_) {
    ushort4 ol;
    ol.x = bfbits(v.x - (float)b0);
    ol.y = bfbits(v.y - (float)b1);
    ol.z = bfbits(v.z - (float)b2);
    ol.w = bfbits(v.w - (float)b3);
    ((ushort4*)lo_)[i] = ol;
  }
}

extern "C" __global__ __launch_bounds__(256) void rmsnorm_kernel(
    const float* __restrict__ x, const float* __restrict__ g,
    unsigned short* __restrict__ yhi, unsigned short* __restrict__ ylo) {
  int row = blockIdx.x;
  int t = threadIdx.x;
  const float4 xv = *(const float4*)(x + (size_t)row * 1024 + t * 4);
  float ss = xv.x * xv.x + xv.y * xv.y + xv.z * xv.z + xv.w * xv.w;
#pragma unroll
  for (int d = 1; d < 64; d <<= 1) ss += __shfl_xor(ss, d, 64);
  __shared__ float red[4];
  if ((t & 63) == 0) red[t >> 6] = ss;
  __syncthreads();
  float tot = red[0] + red[1] + red[2] + red[3];
  float inv = 1.0f / sqrtf(tot * (1.0f / 1024.0f) + 1e-5f);
  const float4 gv = *(const float4*)(g + t * 4);
  float y0 = xv.x * gv.x * inv, y1 = xv.y * gv.y * inv;
  float y2 = xv.z * gv.z * inv, y3 = xv.w * gv.w * inv;
  bf16 b0 = (bf16)y0, b1 = (bf16)y1, b2 = (bf16)y2, b3 = (bf16)y3;
  ushort4 oh;
  oh.x = __builtin_bit_cast(unsigned short, b0);
  oh.y = __builtin_bit_cast(unsigned short, b1);
  oh.z = __builtin_bit_cast(unsigned short, b2);
  oh.w = __builtin_bit_cast(unsigned short, b3);
  ((ushort4*)yhi)[(size_t)row * 256 + t] = oh;
  if (ylo) {
    ushort4 ol;
    ol.x = bfbits(y0 - (float)b0);
    ol.y = bfbits(y1 - (float)b1);
    ol.z = bfbits(y2 - (float)b2);
    ol.w = bfbits(y3 - (float)b3);
    ((ushort4*)ylo)[(size_t)row * 256 + t] = ol;
  }
}

// ---------------- GEMM: C[M,N] = A[M,K(ldk)] * B[N,K(ldk)]^T, 128x128 tile, BK=64 ----------------
// [128][64] LDS tiles, 128B rows, swizzle c ^= r&7. Single-buffered.
// Flat grid, XCD-chunked M-slab. z = sq>>5 = K-slice for split-K.
// EPI 1: +resF -> f32; EPI 5: atomicAdd f32
template <int EPI>
__global__ __launch_bounds__(256, 2) void gemm_nt(
    const bf16* __restrict__ A, const bf16* __restrict__ B, int N, int K, int ldk,
    float* __restrict__ outF, bf16* __restrict__ outB,
    const float* __restrict__ resF) {
  const int bid = blockIdx.x;
  const int xcd = bid & 7, sq = bid >> 3;
  const int z = sq >> 5;
  const int rem = sq & 31;
  const size_t tm = (size_t)(xcd * 4 + (rem >> 3)) * 128;
  const size_t tn = (size_t)(rem & 7) * 128;
  A += (size_t)z * K;
  B += (size_t)z * K;
  __shared__ alignas(16) bf16 As[128 * 64];
  __shared__ alignas(16) bf16 Bs[128 * 64];
  const int tid = threadIdx.x;
  const int lane = tid & 63, wave = tid >> 6;
  const int lo = lane & 15, hi = lane >> 4;
  const int wm = wave >> 1, wn = wave & 1;
  f32x4 acc[4][4] = {};
  for (int k0 = 0; k0 < K; k0 += 64) {
    __syncthreads();
#pragma unroll
    for (int i4 = 0; i4 < 4; i4++) {
      int p = tid + 256 * i4;
      int row = p >> 3, c = p & 7;
      int cs = c ^ (row & 7);
      async_cp16((char*)As + (size_t)p * 16, A + (tm + row) * (size_t)ldk + k0 + cs * 8);
      async_cp16((char*)Bs + (size_t)p * 16, B + (tn + row) * (size_t)ldk + k0 + cs * 8);
    }
    __syncthreads();
#pragma unroll
    for (int kh = 0; kh < 2; kh++) {
      bf16x8 fa[4], fb[4];
#pragma unroll
      for (int i = 0; i < 4; i++) {
        int ra = wm * 64 + i * 16 + lo;
        fa[i] = *(const bf16x8*)((const char*)As + ra * 128 + (((kh * 4 + hi) ^ (ra & 7)) << 4));
        int rb = wn * 64 + i * 16 + lo;
        fb[i] = *(const bf16x8*)((const char*)Bs + rb * 128 + (((kh * 4 + hi) ^ (rb & 7)) << 4));
      }
      __builtin_amdgcn_s_setprio(1);
#pragma unroll
      for (int i = 0; i < 4; i++)
#pragma unroll
        for (int j = 0; j < 4; j++) acc[i][j] = mfma16(fa[i], fb[j], acc[i][j]);
      __builtin_amdgcn_s_setprio(0);
    }
  }
#pragma unroll
  for (int i = 0; i < 4; i++)
#pragma unroll
    for (int j = 0; j < 4; j++)
#pragma unroll
      for (int r = 0; r < 4; r++) {
        size_t m = tm + wm * 64 + i * 16 + hi * 4 + r;
        size_t n = tn + wn * 64 + j * 16 + lo;
        float v = acc[i][j][r];
        if constexpr (EPI == 1) {
          size_t idx = m * (size_t)N + n;
          outF[idx] = v + resF[idx];
        } else {
          atomicAdd(&outF[m * (size_t)N + n], v);
        }
      }
}

// ---------------- fused FFN-up: G = silu(A*B1^T) * (A*B3^T), 128x128, BK=64 ----------------
extern "C" __global__ __launch_bounds__(256, 2) void gemm_up_kernel(
    const bf16* __restrict__ A, const bf16* __restrict__ B1,
    const bf16* __restrict__ B3, bf16* __restrict__ G) {
  const int bid = blockIdx.x;
  const int xcd = bid & 7, sq = bid >> 3;
  const size_t tm = (size_t)(xcd * 4 + (sq & 3)) * 128;
  const size_t tn = (size_t)(sq >> 2) * 128;
  __shared__ alignas(16) bf16 As[128 * 64];
  __shared__ alignas(16) bf16 B1s[128 * 64];
  __shared__ alignas(16) bf16 B3s[128 * 64];
  const int tid = threadIdx.x;
  const int lane = tid & 63, wave = tid >> 6;
  const int lo = lane & 15, hi = lane >> 4;
  const int wm = wave >> 1, wn = wave & 1;
  f32x4 acc1[4][4] = {}, acc3[4][4] = {};
  for (int k0 = 0; k0 < 1024; k0 += 64) {
    __syncthreads();
#pragma unroll
    for (int i4 = 0; i4 < 4; i4++) {
      int p = tid + 256 * i4;
      int row = p >> 3, c = p & 7;
      int cs = c ^ (row & 7);
      async_cp16((char*)As + (size_t)p * 16, A + (tm + row) * (size_t)1024 + k0 + cs * 8);
      async_cp16((char*)B1s + (size_t)p * 16, B1 + (tn + row) * (size_t)1024 + k0 + cs * 8);
      async_cp16((char*)B3s + (size_t)p * 16, B3 + (tn + row) * (size_t)1024 + k0 + cs * 8);
    }
    __syncthreads();
#pragma unroll
    for (int kh = 0; kh < 2; kh++) {
      bf16x8 fa[4], fb[4];
#pragma unroll
      for (int i = 0; i < 4; i++) {
        int ra = wm * 64 + i * 16 + lo;
        fa[i] = *(const bf16x8*)((const char*)As + ra * 128 + (((kh * 4 + hi) ^ (ra & 7)) << 4));
        int rb = wn * 64 + i * 16 + lo;
        fb[i] = *(const bf16x8*)((const char*)B1s + rb * 128 + (((kh * 4 + hi) ^ (rb & 7)) << 4));
      }
      __builtin_amdgcn_s_setprio(1);
#pragma unroll
      for (int i = 0; i < 4; i++)
#pragma unroll
        for (int j = 0; j < 4; j++) acc1[i][j] = mfma16(fa[i], fb[j], acc1[i][j]);
      __builtin_amdgcn_s_setprio(0);
#pragma unroll
      for (int j = 0; j < 4; j++) {
        int rb = wn * 64 + j * 16 + lo;
        fb[j] = *(const bf16x8*)((const char*)B3s + rb * 128 + (((kh * 4 + hi) ^ (rb & 7)) << 4));
      }
      __builtin_amdgcn_s_setprio(1);
#pragma unroll
      for (int i = 0; i < 4; i++)
#pragma unroll
        for (int j = 0; j < 4; j++) acc3[i][j] = mfma16(fa[i], fb[j], acc3[i][j]);
      __builtin_amdgcn_s_setprio(0);
    }
  }
#pragma unroll
  for (int i = 0; i < 4; i++)
#pragma unroll
    for (int j = 0; j < 4; j++)
#pragma unroll
      for (int r = 0; r < 4; r++) {
        size_t m = tm + wm * 64 + i * 16 + hi * 4 + r;
        size_t n = tn + wn * 64 + j * 16 + lo;
        float v1 = acc1[i][j][r], v3 = acc3[i][j][r];
        G[m * 4096 + n] = (bf16)(v1 / (1.0f + __expf(-v1)) * v3);
      }
}

// ---------------- merged QKV: split-precision q/k (3-term, fused RoPE) + plain v (transpose) ----------------
// Grid 768 flat: z = sq>>5 in {0:Q, 1:K, 2:V} — CONTIGUOUS z (R14: interleaved z
// doubled FETCH by thrashing per-XCD L2 across 5 weight streams).
extern "C" __global__ __launch_bounds__(256, 2) void gemm_qkv_kernel(
    const bf16* __restrict__ Ah, const bf16* __restrict__ Al,
    const bf16* __restrict__ BhQ, const bf16* __restrict__ BlQ,
    const bf16* __restrict__ BhK, const bf16* __restrict__ BlK,
    const bf16* __restrict__ BV,
    const float2* __restrict__ rope,
    bf16* __restrict__ OhQ, bf16* __restrict__ OlQ,
    bf16* __restrict__ OhK, bf16* __restrict__ OlK,
    bf16* __restrict__ Vt) {
  const int bid = blockIdx.x;
  const int xcd = bid & 7, sq = bid >> 3;
  const int z = sq >> 5;   // 0:Q 1:K 2:V
  const int rem = sq & 31;
  const size_t tm = (size_t)(xcd * 4 + (rem >> 3)) * 128;
  const size_t tn = (size_t)(rem & 7) * 128;
  const bf16* Bh = (z == 0) ? BhQ : (z == 1) ? BhK : BV;
  const bf16* Bl = (z == 1) ? BlK : BlQ;  // unused when z==2
  __shared__ alignas(16) bf16 Ahs[128 * 64], Als[128 * 64];
  __shared__ alignas(16) bf16 Bhs[128 * 64], Bls[128 * 64];
  const int tid = threadIdx.x;
  const int lane = tid & 63, wave = tid >> 6;
  const int lo = lane & 15, hi = lane >> 4;
  const int wm = wave >> 1, wn = wave & 1;
  const int K = 1024;
  f32x4 acc[4][4] = {};
  for (int k0 = 0; k0 < K; k0 += 64) {
    __syncthreads();
#pragma unroll
    for (int i4 = 0; i4 < 4; i4++) {
      int p = tid + 256 * i4;
      int row = p >> 3, c = p & 7;
      int cs = c ^ (row & 7);
      size_t ga = (tm + row) * (size_t)K + k0 + cs * 8;
      size_t gb = (tn + row) * (size_t)K + k0 + cs * 8;
      async_cp16((char*)Ahs + (size_t)p * 16, Ah + ga);
      async_cp16((char*)Bhs + (size_t)p * 16, Bh + gb);
      if (z < 2) {
        async_cp16((char*)Als + (size_t)p * 16, Al + ga);
        async_cp16((char*)Bls + (size_t)p * 16, Bl + gb);
      }
    }
    __syncthreads();
#pragma unroll
    for (int kh = 0; kh < 2; kh++) {
      int offa[4], offb[4];
#pragma unroll
      for (int i = 0; i < 4; i++) {
        int ra = wm * 64 + i * 16 + lo;
        offa[i] = ra * 128 + (((kh * 4 + hi) ^ (ra & 7)) << 4);
        int rb = wn * 64 + i * 16 + lo;
        offb[i] = rb * 128 + (((kh * 4 + hi) ^ (rb & 7)) << 4);
      }
      bf16x8 fah[4], fbh[4], fx[4];
#pragma unroll
      for (int i = 0; i < 4; i++) {
        fah[i] = *(const bf16x8*)((const char*)Ahs + offa[i]);
        fbh[i] = *(const bf16x8*)((const char*)Bhs + offb[i]);
      }
      __builtin_amdgcn_s_setprio(1);
#pragma unroll
      for (int i = 0; i < 4; i++)
#pragma unroll
        for (int j = 0; j < 4; j++) acc[i][j] = mfma16(fah[i], fbh[j], acc[i][j]);
      __builtin_amdgcn_s_setprio(0);
      if (z < 2) {
#pragma unroll
        for (int j = 0; j < 4; j++) fx[j] = *(const bf16x8*)((const char*)Bls + offb[j]);
        __builtin_amdgcn_s_setprio(1);
#pragma unroll
        for (int i = 0; i < 4; i++)
#pragma unroll
          for (int j = 0; j < 4; j++) acc[i][j] = mfma16(fah[i], fx[j], acc[i][j]);
        __builtin_amdgcn_s_setprio(0);
#pragma unroll
        for (int i = 0; i < 4; i++) fx[i] = *(const bf16x8*)((const char*)Als + offa[i]);
        __builtin_amdgcn_s_setprio(1);
#pragma unroll
        for (int i = 0; i < 4; i++)
#pragma unroll
          for (int j = 0; j < 4; j++) acc[i][j] = mfma16(fx[i], fbh[j], acc[i][j]);
        __builtin_amdgcn_s_setprio(0);
      }
    }
  }
  if (z < 2) {
    bf16* Oh = z ? OhK : OhQ;
    bf16* Ol = z ? OlK : OlQ;
#pragma unroll
    for (int i = 0; i < 4; i++)
#pragma unroll
      for (int j = 0; j < 4; j++)
#pragma unroll
        for (int r = 0; r < 4; r++) {
          float v = acc[i][j][r];
          float vp = __shfl_xor(v, 1, 64);
          size_t m = tm + wm * 64 + i * 16 + hi * 4 + r;
          size_t n = tn + wn * 64 + j * 16 + lo;
          int s = (int)(m & 1023);
          int pi = (int)((n & 63) >> 1);
          float2 cs = rope[s * 32 + pi];
          float res = (n & 1) ? (vp * cs.y + v * cs.x) : (v * cs.x - vp * cs.y);
          size_t idx = (((m >> 10) * 16 + (n >> 6)) * 1024 + (m & 1023)) * 64 + (n & 63);
          bf16 hb = (bf16)res;
          Oh[idx] = hb;
          Ol[idx] = (bf16)(res - (float)hb);
        }
  } else {
#pragma unroll
    for (int i = 0; i < 4; i++)
#pragma unroll
      for (int j = 0; j < 4; j++)
#pragma unroll
        for (int r = 0; r < 4; r++) {
          size_t m = tm + wm * 64 + i * 16 + hi * 4 + r;
          size_t n = tn + wn * 64 + j * 16 + lo;
          size_t idx = (((m >> 10) * 16 + (n >> 6)) * 64 + (n & 63)) * 1024 + (m & 1023);
          Vt[idx] = (bf16)acc[i][j][r];
        }
  }
}

// ---------------- flash attention (causal), split-precision scores, LDS-staged K/V ----------------
extern "C" __global__ __launch_bounds__(256, 4) void flash_kernel(
    const bf16* __restrict__ qhi, const bf16* __restrict__ qlo,
    const bf16* __restrict__ khi, const bf16* __restrict__ klo,
    const bf16* __restrict__ vT, bf16* __restrict__ ctx) {
  const int bid = blockIdx.x;
  const int qb = bid >> 6;
  const int bh = bid & 63;
  const int tid = threadIdx.x;
  const int wave = tid >> 6, lane = tid & 63;
  const int lo = lane & 15, hi = lane >> 4;

  __shared__ alignas(16) bf16 Ksh[2][64][32];
  __shared__ alignas(16) bf16 Ksl[2][64][32];
  __shared__ alignas(16) bf16 Vs[2][64][32];
  __shared__ alignas(16) bf16 P[4][16][72];

  size_t qoff = ((size_t)bh * 1024 + qb * 64 + wave * 16 + lo) * 64;
  bf16x8 qh[2], ql[2];
#pragma unroll
  for (int ks = 0; ks < 2; ks++) {
    qh[ks] = *(const bf16x8*)(qhi + qoff + ks * 32 + hi * 8);
    ql[ks] = *(const bf16x8*)(qlo + qoff + ks * 32 + hi * 8);
  }

  const int srow = tid >> 2;
  const int scl = (tid & 3) ^ swz4(srow);
  const size_t kgb = (size_t)bh * 1024 * 64;
  const size_t vgb = ((size_t)bh * 64 + srow) * 1024;

  float mrun[4] = {-1e30f, -1e30f, -1e30f, -1e30f};
  float lrun[4] = {0.f, 0.f, 0.f, 0.f};
  f32x4 o[4] = {};
  const float scale = 0.125f;

  for (int kt = 0; kt <= qb; kt++) {
    __syncthreads();
#pragma unroll
    for (int i = 0; i < 2; i++) {
      int p = tid + 256 * i;
      size_t gk = kgb + (size_t)(kt * 64 + srow) * 64 + i * 32 + scl * 8;
      async_cp16((char*)Ksh + (size_t)p * 16, khi + gk);
      async_cp16((char*)Ksl + (size_t)p * 16, klo + gk);
      async_cp16((char*)Vs + (size_t)p * 16, vT + vgb + kt * 64 + i * 32 + scl * 8);
    }
    __syncthreads();

    f32x4 sv[4];
    __builtin_amdgcn_s_setprio(1);
#pragma unroll
    for (int nb = 0; nb < 4; nb++) {
      f32x4 a = {0.f, 0.f, 0.f, 0.f};
#pragma unroll
      for (int ks = 0; ks < 2; ks++) {
        int row = nb * 16 + lo;
        int off16 = (ks * 64 + row) * 4 + (hi ^ swz4(row));
        bf16x8 kh = *(const bf16x8*)((const char*)Ksh + off16 * 16);
        bf16x8 kl = *(const bf16x8*)((const char*)Ksl + off16 * 16);
        a = mfma16(qh[ks], kh, a);
        a = mfma16(qh[ks], kl, a);
        a = mfma16(ql[ks], kh, a);
      }
      sv[nb] = a;
    }
    __builtin_amdgcn_s_setprio(0);

    const bool mt = (kt == qb);
#pragma unroll
    for (int nb = 0; nb < 4; nb++)
#pragma unroll
      for (int r = 0; r < 4; r++) {
        float s = sv[nb][r] * scale;
        if (mt) {
          int kp = nb * 16 + lo;
          int qr = wave * 16 + hi * 4 + r;
          if (kp > qr) s = -1e30f;
        }
        sv[nb][r] = s;
      }
    float mnew[4], rs[4];
#pragma unroll
    for (int r = 0; r < 4; r++) {
      float mx = fmaxf(fmaxf(sv[0][r], sv[1][r]), fmaxf(sv[2][r], sv[3][r]));
#pragma unroll
      for (int d = 1; d < 16; d <<= 1) mx = fmaxf(mx, __shfl_xor(mx, d, 64));
      mnew[r] = fmaxf(mrun[r], mx);
      float sc = __expf(mrun[r] - mnew[r]);
      lrun[r] *= sc;
#pragma unroll
      for (int db = 0; db < 4; db++) o[db][r] *= sc;
      mrun[r] = mnew[r];
      rs[r] = 0.f;
    }
#pragma unroll
    for (int nb = 0; nb < 4; nb++)
#pragma unroll
      for (int r = 0; r < 4; r++) {
        float p = __expf(sv[nb][r] - mnew[r]);
        bf16 pb = (bf16)p;
        rs[r] += (float)pb;
        P[wave][hi * 4 + r][nb * 16 + lo] = pb;
      }
#pragma unroll
    for (int r = 0; r < 4; r++) {
      float t = rs[r];
#pragma unroll
      for (int d = 1; d < 16; d <<= 1) t += __shfl_xor(t, d, 64);
      lrun[r] += t;
    }
    bf16x8 pa[2];
#pragma unroll
    for (int ks = 0; ks < 2; ks++) pa[ks] = *(const bf16x8*)&P[wave][lo][ks * 32 + hi * 8];
    __builtin_amdgcn_s_setprio(1);
#pragma unroll
    for (int db = 0; db < 4; db++)
#pragma unroll
      for (int ks = 0; ks < 2; ks++) {
        int row = db * 16 + lo;
        int off16 = (ks * 64 + row) * 4 + (hi ^ swz4(row));
        bf16x8 vf = *(const bf16x8*)((const char*)Vs + off16 * 16);
        o[db] = mfma16(pa[ks], vf, o[db]);
      }
    __builtin_amdgcn_s_setprio(0);
  }
  int b = bh >> 4, h = bh & 15;
#pragma unroll
  for (int db = 0; db < 4; db++)
#pragma unroll
    for (int r = 0; r < 4; r++) {
      float val = o[db][r] / lrun[r];
      size_t row = (size_t)b * 1024 + qb * 64 + wave * 16 + hi * 4 + r;
      ctx[row * 1024 + h * 64 + db * 16 + lo] = (bf16)val;
    }
}

// ---------------- host launcher ----------------

extern "C" void kernel_launch(void* const* d_in, const int* in_sizes, int n_in,
                              void* d_out, int out_size, void* d_ws, size_t ws_size,
                              hipStream_t stream) {
  (void)in_sizes; (void)n_in; (void)out_size; (void)ws_size;
  const float* x  = (const float*)d_in[0];
  const float* wq = (const float*)d_in[1];
  const float* wk = (const float*)d_in[2];
  const float* wv = (const float*)d_in[3];
  const float* wo = (const float*)d_in[4];
  const float* w1 = (const float*)d_in[5];
  const float* w2 = (const float*)d_in[6];
  const float* w3 = (const float*)d_in[7];
  const float* g1 = (const float*)d_in[8];
  const float* g2 = (const float*)d_in[9];
  float* out = (float*)d_out;

  char* ws = (char*)d_ws;
  size_t off = 0;
  auto alloc = [&](size_t bytes) {
    char* p = ws + off;
    off += (bytes + 255) & ~(size_t)255;
    return p;
  };
  const size_t MB2 = 1024u * 1024u * 2u;
  const size_t MB8 = 4096u * 1024u * 2u;
  void* WQH = alloc(MB2);  void* WQL = alloc(MB2);
  void* WKH = alloc(MB2);  void* WKL = alloc(MB2);
  void* WVH = alloc(MB2);  void* WOH = alloc(MB2);
  void* W1H = alloc(MB8);  void* W3H = alloc(MB8);  void* W2H = alloc(MB8);
  void* ROPE = alloc(32768u * 8u);
  void* Y1H = alloc(MB8);  void* Y1L = alloc(MB8);
  void* QH = alloc(MB8);   void* QL = alloc(MB8);
  void* KH = alloc(MB8);   void* KL = alloc(MB8);
  void* VT = alloc(MB8);
  void* CTX = alloc(MB8);
  void* Y2H = alloc(MB8);
  void* GLU = QH;  // 32MB alias over QH,QL,KH,KL (dead after flash)

  prep_kernel<<<dim3(4096, 8), dim3(256), 0, stream>>>(
      wq, wk, wv, wo, w1, w3, w2,
      (unsigned short*)WQH, (unsigned short*)WQL, (unsigned short*)WKH,
      (unsigned short*)WKL, (unsigned short*)WVH, (unsigned short*)WOH,
      (unsigned short*)W1H, (unsigned short*)W3H, (unsigned short*)W2H,
      (float2*)ROPE);

  rmsnorm_kernel<<<dim3(4096), dim3(256), 0, stream>>>(
      x, g1, (unsigned short*)Y1H, (unsigned short*)Y1L);

  // merged QKV: q,k split-precision (3-term) + v plain, one 768-block launch
  gemm_qkv_kernel<<<dim3(768), dim3(256), 0, stream>>>(
      (const bf16*)Y1H, (const bf16*)Y1L,
      (const bf16*)WQH, (const bf16*)WQL, (const bf16*)WKH, (const bf16*)WKL,
      (const bf16*)WVH,
      (const float2*)ROPE,
      (bf16*)QH, (bf16*)QL, (bf16*)KH, (bf16*)KL, (bf16*)VT);

  flash_kernel<<<dim3(1024), dim3(256), 0, stream>>>(
      (const bf16*)QH, (const bf16*)QL, (const bf16*)KH, (const bf16*)KL,
      (const bf16*)VT, (bf16*)CTX);

  gemm_nt<1><<<dim3(256), dim3(256), 0, stream>>>(
      (const bf16*)CTX, (const bf16*)WOH, 1024, 1024, 1024,
      out, nullptr, x);

  rmsnorm_kernel<<<dim3(4096), dim3(256), 0, stream>>>(
      out, g2, (unsigned short*)Y2H, nullptr);

  gemm_up_kernel<<<dim3(1024), dim3(256), 0, stream>>>(
      (const bf16*)Y2H, (const bf16*)W1H, (const bf16*)W3H, (bf16*)GLU);

  // down-projection: split-K=2 (512 blocks, K=2048), atomic f32 accumulate
  gemm_nt<5><<<dim3(512), dim3(256), 0, stream>>>(
      (const bf16*)GLU, (const bf16*)W2H, 1024, 2048, 4096,
      out, nullptr, nullptr);
}